// Round 10
// baseline (83.826 us; speedup 1.0000x reference)
//
#include <hip/hip_runtime.h>
#include <hip/hip_bf16.h>

typedef __bf16 bf16x8 __attribute__((ext_vector_type(8)));
typedef float f32x4 __attribute__((ext_vector_type(4)));
typedef unsigned int u32;
typedef u32 u32x4 __attribute__((ext_vector_type(4)));

#define BN_EPS 1e-5f

// ---------------- prepass 1: fp32 table -> bf16 table ----------------
__global__ __launch_bounds__(256) void convert_kernel(
    const float* __restrict__ vf, __bf16* __restrict__ tb, int n8)
{
    int i = blockIdx.x * blockDim.x + threadIdx.x;
    const int stride = gridDim.x * blockDim.x;
    for (; i < n8; i += stride) {
        const f32x4 a = ((const f32x4*)vf)[2 * i];
        const f32x4 b = ((const f32x4*)vf)[2 * i + 1];
        bf16x8 o;
        o[0]=(__bf16)a.x; o[1]=(__bf16)a.y; o[2]=(__bf16)a.z; o[3]=(__bf16)a.w;
        o[4]=(__bf16)b.x; o[5]=(__bf16)b.y; o[6]=(__bf16)b.z; o[7]=(__bf16)b.w;
        ((bf16x8*)tb)[i] = o;
    }
}

// ---------------- prepass 2: pack W frags + BN affine + zero row ----------------
__global__ __launch_bounds__(64) void pack_kernel(
    const float* __restrict__ W, const float* __restrict__ bias,
    const float* __restrict__ gamma, const float* __restrict__ beta,
    const float* __restrict__ mean, const float* __restrict__ var,
    __bf16* __restrict__ tb, u32* __restrict__ packB,
    float* __restrict__ SP, float* __restrict__ TP, int N)
{
    const int lane = threadIdx.x;
    const int col = lane & 15, grp = lane >> 4, c0 = grp << 3;
    if (lane < 16) ((u32*)(tb + (size_t)N * 32))[lane] = 0u;   // zero row
    f32x4 s4, t4;
#pragma unroll
    for (int t = 0; t < 4; ++t) {
        const int o = t * 16 + col;
        const f32x4 w0 = *(const f32x4*)(W + o * 32 + c0);
        const f32x4 w1 = *(const f32x4*)(W + o * 32 + c0 + 4);
        bf16x8 f;
        f[0]=(__bf16)w0.x; f[1]=(__bf16)w0.y; f[2]=(__bf16)w0.z; f[3]=(__bf16)w0.w;
        f[4]=(__bf16)w1.x; f[5]=(__bf16)w1.y; f[6]=(__bf16)w1.z; f[7]=(__bf16)w1.w;
        ((bf16x8*)packB)[t * 64 + lane] = f;
        const float s = gamma[o] * rsqrtf(var[o] + BN_EPS);
        s4[t] = s;
        t4[t] = (bias[o] - mean[o]) * s + beta[o];
    }
    ((f32x4*)SP)[lane] = s4;
    ((f32x4*)TP)[lane] = t4;
}

// ---------------- main: one-shot wave = 4 rows, MAX OCCUPANCY ----------------
// The binding constraint R3-R8 never moved: resident waves/CU (launch_bounds
// (256,4) capped 16/CU). Gather service is latency-bound (Q/L, L~500cy L3);
// Q = waves x depth. Depth is compiler-clamped at ~8, so double WAVES:
// __launch_bounds__(256, 8) -> 32 waves/CU target, VGPR budget 64 (R3's
// structure measured 44). Spill tripwire: WRITE_SIZE must stay 25 MB.
__global__ __launch_bounds__(256, 8) void down_bf16(
    const __bf16* __restrict__ tb,    // [N+1,32] bf16 (row N = zeros)
    const int*   __restrict__ kidx,   // [M,32]
    const int*   __restrict__ kmask,  // [M,32] (1 = invalid)
    const u32*   __restrict__ packB,
    const float* __restrict__ SP,
    const float* __restrict__ TP,
    float* __restrict__ out,          // [M,64]
    int M, int N)
{
    const int lane = threadIdx.x & 63;
    const int col  = lane & 15;
    const int grp  = lane >> 4;
    const int c0   = grp << 3;

    const int wave_id = blockIdx.x * 4 + (threadIdx.x >> 6);
    const int m0 = wave_id * 4;            // 4 rows per wave, one-shot
    if (m0 >= M) return;

    // ---- coalesced idx/mask: 4 rows x 32 = 128 elems = 2 loads each ----
    const int elim  = M * 32 - 1;
    const int ebase = m0 * 32 + lane;
    int ci[2], cm[2];
#pragma unroll
    for (int i = 0; i < 2; ++i) {
        int e = ebase + i * 64; e = e < elim ? e : elim;
        ci[i] = __builtin_nontemporal_load(kidx + e);
    }
#pragma unroll
    for (int i = 0; i < 2; ++i) {
        int e = ebase + i * 64; e = e < elim ? e : elim;
        cm[i] = __builtin_nontemporal_load(kmask + e);
    }

    // ---- B frags + BN affine (L2-hot, same addr across all waves) ----
    bf16x8 bfrag[4];
#pragma unroll
    for (int t = 0; t < 4; ++t)
        bfrag[t] = ((const bf16x8*)packB)[t * 64 + lane];
    const f32x4 Sv = ((const f32x4*)SP)[lane];
    const f32x4 Tv = ((const f32x4*)TP)[lane];

    // ---- shfl-redistribute idx/mask to gather lanes; fold mask -> zero row ----
    // elem(r,kt,col) = r*32 + kt*16 + col -> load (r>>1), srclane ((r&1)<<5)+(kt<<4)+col
    int fid[4][2];
#pragma unroll
    for (int r = 0; r < 4; ++r)
#pragma unroll
        for (int kt = 0; kt < 2; ++kt) {
            const int srcl = ((r & 1) << 5) + (kt << 4) + col;
            int idv = __shfl(ci[r >> 1], srcl, 64);
            int mkv = __shfl(cm[r >> 1], srcl, 64);
            idv = idv < 0 ? 0 : idv;
            fid[r][kt] = (mkv == 0) ? idv : N;
        }

    // ---- issue ALL 8 gathers (one dwordx4 each) ----
    u32x4 g[4][2];
#pragma unroll
    for (int r = 0; r < 4; ++r)
#pragma unroll
        for (int kt = 0; kt < 2; ++kt)
            g[r][kt] = *(const u32x4*)(tb + (size_t)fid[r][kt] * 32 + c0);

    // ---- MFMA + fused BN/ReLU/max + store ----
    const f32x4 zero4 = {0.f, 0.f, 0.f, 0.f};
#pragma unroll
    for (int r = 0; r < 4; ++r) {
        const int m = m0 + r;
        const bf16x8 a0 = __builtin_bit_cast(bf16x8, g[r][0]);
        const bf16x8 a1 = __builtin_bit_cast(bf16x8, g[r][1]);
        float myout = 0.0f;
#pragma unroll
        for (int t = 0; t < 4; ++t) {
            f32x4 d0 = __builtin_amdgcn_mfma_f32_16x16x32_bf16(a0, bfrag[t], zero4, 0, 0, 0);
            f32x4 d1 = __builtin_amdgcn_mfma_f32_16x16x32_bf16(a1, bfrag[t], zero4, 0, 0, 0);
            float v = 0.0f;   // ReLU folded into max
#pragma unroll
            for (int q = 0; q < 4; ++q) {
                v = fmaxf(v, d0[q] * Sv[t] + Tv[t]);
                v = fmaxf(v, d1[q] * Sv[t] + Tv[t]);
            }
            v = fmaxf(v, __shfl_xor(v, 16));
            v = fmaxf(v, __shfl_xor(v, 32));
            if (grp == t) myout = v;
        }
        if (m < M) __builtin_nontemporal_store(myout, out + (size_t)m * 64 + lane);
    }
}

// ---------------- fallback (fp32 gather, no workspace) ----------------
__global__ __launch_bounds__(256, 4) void down_fp32(
    const float* __restrict__ vf, const int* __restrict__ kidx,
    const int* __restrict__ kmask, const float* __restrict__ W,
    const float* __restrict__ bias, const float* __restrict__ gamma,
    const float* __restrict__ beta, const float* __restrict__ mean,
    const float* __restrict__ var, float* __restrict__ out, int M)
{
    const int lane = threadIdx.x & 63;
    const int col  = lane & 15;
    const int grp  = lane >> 4;
    const int c0   = grp << 3;
    const int waves_per_block = blockDim.x >> 6;
    const int wave_id     = blockIdx.x * waves_per_block + (threadIdx.x >> 6);
    const int total_waves = gridDim.x * waves_per_block;

    bf16x8 bfrag[4];
    float S[4], T[4];
#pragma unroll
    for (int t = 0; t < 4; ++t) {
        const int o = t * 16 + col;
        const f32x4 w0 = *(const f32x4*)(W + o * 32 + c0);
        const f32x4 w1 = *(const f32x4*)(W + o * 32 + c0 + 4);
        bf16x8 f;
        f[0]=(__bf16)w0.x; f[1]=(__bf16)w0.y; f[2]=(__bf16)w0.z; f[3]=(__bf16)w0.w;
        f[4]=(__bf16)w1.x; f[5]=(__bf16)w1.y; f[6]=(__bf16)w1.z; f[7]=(__bf16)w1.w;
        bfrag[t] = f;
        const float s = gamma[o] * rsqrtf(var[o] + BN_EPS);
        S[t] = s;
        T[t] = (bias[o] - mean[o]) * s + beta[o];
    }
    const f32x4 zero4 = {0.f, 0.f, 0.f, 0.f};
    for (int m = wave_id; m < M; m += total_waves) {
        const int* idxp = kidx  + (size_t)m * 32;
        const int* mskp = kmask + (size_t)m * 32;
        bf16x8 afrag[2];
#pragma unroll
        for (int kt = 0; kt < 2; ++kt) {
            const int k = kt * 16 + col;
            int id = idxp[k]; id = id < 0 ? 0 : id;
            const float sel = (mskp[k] == 0) ? 1.0f : 0.0f;
            const float* src = vf + (size_t)id * 32 + c0;
            const f32x4 g0 = *(const f32x4*)(src);
            const f32x4 g1 = *(const f32x4*)(src + 4);
            bf16x8 a;
            a[0]=(__bf16)(g0.x*sel); a[1]=(__bf16)(g0.y*sel);
            a[2]=(__bf16)(g0.z*sel); a[3]=(__bf16)(g0.w*sel);
            a[4]=(__bf16)(g1.x*sel); a[5]=(__bf16)(g1.y*sel);
            a[6]=(__bf16)(g1.z*sel); a[7]=(__bf16)(g1.w*sel);
            afrag[kt] = a;
        }
        float myout = 0.0f;
#pragma unroll
        for (int t = 0; t < 4; ++t) {
            f32x4 d0 = __builtin_amdgcn_mfma_f32_16x16x32_bf16(afrag[0], bfrag[t], zero4, 0, 0, 0);
            f32x4 d1 = __builtin_amdgcn_mfma_f32_16x16x32_bf16(afrag[1], bfrag[t], zero4, 0, 0, 0);
            float v = 0.0f;
#pragma unroll
            for (int q = 0; q < 4; ++q) {
                v = fmaxf(v, d0[q] * S[t] + T[t]);
                v = fmaxf(v, d1[q] * S[t] + T[t]);
            }
            v = fmaxf(v, __shfl_xor(v, 16));
            v = fmaxf(v, __shfl_xor(v, 32));
            if (grp == t) myout = v;
        }
        out[(size_t)m * 64 + lane] = myout;
    }
}

extern "C" void kernel_launch(void* const* d_in, const int* in_sizes, int n_in,
                              void* d_out, int out_size, void* d_ws, size_t ws_size,
                              hipStream_t stream) {
    const float* vf    = (const float*)d_in[0];
    const int*   kidx  = (const int*)  d_in[1];
    const int*   kmask = (const int*)  d_in[2];
    const float* W     = (const float*)d_in[3];
    const float* bias  = (const float*)d_in[4];
    const float* gamma = (const float*)d_in[5];
    const float* beta  = (const float*)d_in[6];
    const float* mean  = (const float*)d_in[7];
    const float* var   = (const float*)d_in[8];
    float* out = (float*)d_out;

    const int NC = in_sizes[0];        // N*32 floats
    const int N  = NC / 32;
    const int M  = in_sizes[1] / 32;   // key_indices is [M,32]

    const size_t tbBytes = ((size_t)N + 1) * 32 * sizeof(__bf16);
    const size_t packOff = tbBytes;
    const size_t need    = packOff + 4096 + 1024 + 1024;

    if (ws_size >= need) {
        __bf16* tb    = (__bf16*)d_ws;
        u32*    packB = (u32*)  ((char*)d_ws + packOff);
        float*  SP    = (float*)((char*)d_ws + packOff + 4096);
        float*  TP    = (float*)((char*)d_ws + packOff + 4096 + 1024);

        pack_kernel<<<1, 64, 0, stream>>>(W, bias, gamma, beta, mean, var,
                                          tb, packB, SP, TP, N);
        convert_kernel<<<2048, 256, 0, stream>>>(vf, tb, NC / 8);

        const int rows_per_block = 16;          // 4 waves x 4 rows
        const int blocks = (M + rows_per_block - 1) / rows_per_block;
        down_bf16<<<blocks, 256, 0, stream>>>(tb, kidx, kmask, packB, SP, TP,
                                              out, M, N);
    } else {
        down_fp32<<<2048, 256, 0, stream>>>(vf, kidx, kmask, W, bias, gamma,
                                            beta, mean, var, out, M);
    }
}

// Round 11
// 53.233 us; speedup vs baseline: 1.5747x; 1.5747x over previous
//
#include <hip/hip_runtime.h>
#include <hip/hip_bf16.h>

typedef __bf16 bf16x8 __attribute__((ext_vector_type(8)));
typedef float f32x4 __attribute__((ext_vector_type(4)));
typedef unsigned int u32;
typedef u32 u32x4 __attribute__((ext_vector_type(4)));

#define BN_EPS 1e-5f

// ---- fused prepass: fp32 table -> bf16 table (+zero row), block 0 packs W/BN ----
__global__ __launch_bounds__(256) void prep_kernel(
    const float* __restrict__ vf,
    const float* __restrict__ W, const float* __restrict__ bias,
    const float* __restrict__ gamma, const float* __restrict__ beta,
    const float* __restrict__ mean, const float* __restrict__ var,
    __bf16* __restrict__ tb, u32* __restrict__ packB,
    float* __restrict__ SP, float* __restrict__ TP,
    int n8, int N)
{
    if (blockIdx.x == 0 && threadIdx.x < 64) {
        const int lane = threadIdx.x;
        const int col = lane & 15, grp = lane >> 4, c0 = grp << 3;
        if (lane < 16) ((u32*)(tb + (size_t)N * 32))[lane] = 0u;   // zero row
        f32x4 s4, t4;
#pragma unroll
        for (int t = 0; t < 4; ++t) {
            const int o = t * 16 + col;
            const f32x4 w0 = *(const f32x4*)(W + o * 32 + c0);
            const f32x4 w1 = *(const f32x4*)(W + o * 32 + c0 + 4);
            bf16x8 f;
            f[0]=(__bf16)w0.x; f[1]=(__bf16)w0.y; f[2]=(__bf16)w0.z; f[3]=(__bf16)w0.w;
            f[4]=(__bf16)w1.x; f[5]=(__bf16)w1.y; f[6]=(__bf16)w1.z; f[7]=(__bf16)w1.w;
            ((bf16x8*)packB)[t * 64 + lane] = f;
            const float s = gamma[o] * rsqrtf(var[o] + BN_EPS);
            s4[t] = s;
            t4[t] = (bias[o] - mean[o]) * s + beta[o];
        }
        ((f32x4*)SP)[lane] = s4;
        ((f32x4*)TP)[lane] = t4;
    }
    int i = blockIdx.x * blockDim.x + threadIdx.x;
    const int stride = gridDim.x * blockDim.x;
    for (; i < n8; i += stride) {
        const f32x4 a = ((const f32x4*)vf)[2 * i];
        const f32x4 b = ((const f32x4*)vf)[2 * i + 1];
        bf16x8 o;
        o[0]=(__bf16)a.x; o[1]=(__bf16)a.y; o[2]=(__bf16)a.z; o[3]=(__bf16)a.w;
        o[4]=(__bf16)b.x; o[5]=(__bf16)b.y; o[6]=(__bf16)b.z; o[7]=(__bf16)b.w;
        ((bf16x8*)tb)[i] = o;
    }
}

// ---------------- main: one-shot, wave = 8 rows (best measured structure) ----
// At the random-gather service wall (~0.10 lines/cy/CU): per-wave depth is
// compiler-clamped ~8 (R5-R8), extra occupancy queues rather than speeds (R9).
// Keep VGPR <= 64 with no spills: WRITE_SIZE must stay 25 MB.
__global__ __launch_bounds__(256, 4) void down_bf16(
    const __bf16* __restrict__ tb,    // [N+1,32] bf16 (row N = zeros)
    const int*   __restrict__ kidx,   // [M,32]
    const int*   __restrict__ kmask,  // [M,32] (1 = invalid)
    const u32*   __restrict__ packB,
    const float* __restrict__ SP,
    const float* __restrict__ TP,
    float* __restrict__ out,          // [M,64]
    int M, int N)
{
    const int lane = threadIdx.x & 63;
    const int col  = lane & 15;
    const int grp  = lane >> 4;
    const int c0   = grp << 3;

    const int wave_id = blockIdx.x * 4 + (threadIdx.x >> 6);
    const int m0 = wave_id * 8;            // 8 rows per wave, one-shot
    if (m0 >= M) return;

    // ---- coalesced idx/mask: 8 rows x 32 = 256 elems = 4 loads each ----
    const int elim  = M * 32 - 1;
    const int ebase = m0 * 32 + lane;
    int ci[4], cm[4];
#pragma unroll
    for (int i = 0; i < 4; ++i) {
        int e = ebase + i * 64; e = e < elim ? e : elim;
        ci[i] = __builtin_nontemporal_load(kidx + e);
    }
#pragma unroll
    for (int i = 0; i < 4; ++i) {
        int e = ebase + i * 64; e = e < elim ? e : elim;
        cm[i] = __builtin_nontemporal_load(kmask + e);
    }

    // ---- B frags + BN affine (L2-hot, same addr across all waves) ----
    bf16x8 bfrag[4];
#pragma unroll
    for (int t = 0; t < 4; ++t)
        bfrag[t] = ((const bf16x8*)packB)[t * 64 + lane];
    const f32x4 Sv = ((const f32x4*)SP)[lane];
    const f32x4 Tv = ((const f32x4*)TP)[lane];

    // ---- shfl-redistribute idx/mask to gather lanes; fold mask -> zero row ----
    int fid[8][2];
#pragma unroll
    for (int r = 0; r < 8; ++r)
#pragma unroll
        for (int kt = 0; kt < 2; ++kt) {
            const int srcl = ((r & 1) << 5) + (kt << 4) + col;
            int idv = __shfl(ci[r >> 1], srcl, 64);
            int mkv = __shfl(cm[r >> 1], srcl, 64);
            idv = idv < 0 ? 0 : idv;
            fid[r][kt] = (mkv == 0) ? idv : N;
        }

    // ---- issue ALL 16 gathers (one dwordx4 each) ----
    u32x4 g[8][2];
#pragma unroll
    for (int r = 0; r < 8; ++r)
#pragma unroll
        for (int kt = 0; kt < 2; ++kt)
            g[r][kt] = *(const u32x4*)(tb + (size_t)fid[r][kt] * 32 + c0);

    // ---- MFMA + fused BN/ReLU/max + store ----
    const f32x4 zero4 = {0.f, 0.f, 0.f, 0.f};
#pragma unroll
    for (int r = 0; r < 8; ++r) {
        const int m = m0 + r;
        const bf16x8 a0 = __builtin_bit_cast(bf16x8, g[r][0]);
        const bf16x8 a1 = __builtin_bit_cast(bf16x8, g[r][1]);
        float myout = 0.0f;
#pragma unroll
        for (int t = 0; t < 4; ++t) {
            f32x4 d0 = __builtin_amdgcn_mfma_f32_16x16x32_bf16(a0, bfrag[t], zero4, 0, 0, 0);
            f32x4 d1 = __builtin_amdgcn_mfma_f32_16x16x32_bf16(a1, bfrag[t], zero4, 0, 0, 0);
            float v = 0.0f;   // ReLU folded into max
#pragma unroll
            for (int q = 0; q < 4; ++q) {
                v = fmaxf(v, d0[q] * Sv[t] + Tv[t]);
                v = fmaxf(v, d1[q] * Sv[t] + Tv[t]);
            }
            v = fmaxf(v, __shfl_xor(v, 16));
            v = fmaxf(v, __shfl_xor(v, 32));
            if (grp == t) myout = v;
        }
        if (m < M) __builtin_nontemporal_store(myout, out + (size_t)m * 64 + lane);
    }
}

// ---------------- fallback (fp32 gather, no workspace) ----------------
__global__ __launch_bounds__(256, 4) void down_fp32(
    const float* __restrict__ vf, const int* __restrict__ kidx,
    const int* __restrict__ kmask, const float* __restrict__ W,
    const float* __restrict__ bias, const float* __restrict__ gamma,
    const float* __restrict__ beta, const float* __restrict__ mean,
    const float* __restrict__ var, float* __restrict__ out, int M)
{
    const int lane = threadIdx.x & 63;
    const int col  = lane & 15;
    const int grp  = lane >> 4;
    const int c0   = grp << 3;
    const int waves_per_block = blockDim.x >> 6;
    const int wave_id     = blockIdx.x * waves_per_block + (threadIdx.x >> 6);
    const int total_waves = gridDim.x * waves_per_block;

    bf16x8 bfrag[4];
    float S[4], T[4];
#pragma unroll
    for (int t = 0; t < 4; ++t) {
        const int o = t * 16 + col;
        const f32x4 w0 = *(const f32x4*)(W + o * 32 + c0);
        const f32x4 w1 = *(const f32x4*)(W + o * 32 + c0 + 4);
        bf16x8 f;
        f[0]=(__bf16)w0.x; f[1]=(__bf16)w0.y; f[2]=(__bf16)w0.z; f[3]=(__bf16)w0.w;
        f[4]=(__bf16)w1.x; f[5]=(__bf16)w1.y; f[6]=(__bf16)w1.z; f[7]=(__bf16)w1.w;
        bfrag[t] = f;
        const float s = gamma[o] * rsqrtf(var[o] + BN_EPS);
        S[t] = s;
        T[t] = (bias[o] - mean[o]) * s + beta[o];
    }
    const f32x4 zero4 = {0.f, 0.f, 0.f, 0.f};
    for (int m = wave_id; m < M; m += total_waves) {
        const int* idxp = kidx  + (size_t)m * 32;
        const int* mskp = kmask + (size_t)m * 32;
        bf16x8 afrag[2];
#pragma unroll
        for (int kt = 0; kt < 2; ++kt) {
            const int k = kt * 16 + col;
            int id = idxp[k]; id = id < 0 ? 0 : id;
            const float sel = (mskp[k] == 0) ? 1.0f : 0.0f;
            const float* src = vf + (size_t)id * 32 + c0;
            const f32x4 g0 = *(const f32x4*)(src);
            const f32x4 g1 = *(const f32x4*)(src + 4);
            bf16x8 a;
            a[0]=(__bf16)(g0.x*sel); a[1]=(__bf16)(g0.y*sel);
            a[2]=(__bf16)(g0.z*sel); a[3]=(__bf16)(g0.w*sel);
            a[4]=(__bf16)(g1.x*sel); a[5]=(__bf16)(g1.y*sel);
            a[6]=(__bf16)(g1.z*sel); a[7]=(__bf16)(g1.w*sel);
            afrag[kt] = a;
        }
        float myout = 0.0f;
#pragma unroll
        for (int t = 0; t < 4; ++t) {
            f32x4 d0 = __builtin_amdgcn_mfma_f32_16x16x32_bf16(afrag[0], bfrag[t], zero4, 0, 0, 0);
            f32x4 d1 = __builtin_amdgcn_mfma_f32_16x16x32_bf16(afrag[1], bfrag[t], zero4, 0, 0, 0);
            float v = 0.0f;
#pragma unroll
            for (int q = 0; q < 4; ++q) {
                v = fmaxf(v, d0[q] * S[t] + T[t]);
                v = fmaxf(v, d1[q] * S[t] + T[t]);
            }
            v = fmaxf(v, __shfl_xor(v, 16));
            v = fmaxf(v, __shfl_xor(v, 32));
            if (grp == t) myout = v;
        }
        out[(size_t)m * 64 + lane] = myout;
    }
}

extern "C" void kernel_launch(void* const* d_in, const int* in_sizes, int n_in,
                              void* d_out, int out_size, void* d_ws, size_t ws_size,
                              hipStream_t stream) {
    const float* vf    = (const float*)d_in[0];
    const int*   kidx  = (const int*)  d_in[1];
    const int*   kmask = (const int*)  d_in[2];
    const float* W     = (const float*)d_in[3];
    const float* bias  = (const float*)d_in[4];
    const float* gamma = (const float*)d_in[5];
    const float* beta  = (const float*)d_in[6];
    const float* mean  = (const float*)d_in[7];
    const float* var   = (const float*)d_in[8];
    float* out = (float*)d_out;

    const int NC = in_sizes[0];        // N*32 floats
    const int N  = NC / 32;
    const int M  = in_sizes[1] / 32;   // key_indices is [M,32]

    const size_t tbBytes = ((size_t)N + 1) * 32 * sizeof(__bf16);
    const size_t packOff = tbBytes;
    const size_t need    = packOff + 4096 + 1024 + 1024;

    if (ws_size >= need) {
        __bf16* tb    = (__bf16*)d_ws;
        u32*    packB = (u32*)  ((char*)d_ws + packOff);
        float*  SP    = (float*)((char*)d_ws + packOff + 4096);
        float*  TP    = (float*)((char*)d_ws + packOff + 4096 + 1024);

        prep_kernel<<<2048, 256, 0, stream>>>(vf, W, bias, gamma, beta, mean,
                                              var, tb, packB, SP, TP, NC / 8, N);

        const int rows_per_block = 32;          // 4 waves x 8 rows
        const int blocks = (M + rows_per_block - 1) / rows_per_block;
        down_bf16<<<blocks, 256, 0, stream>>>(tb, kidx, kmask, packB, SP, TP,
                                              out, M, N);
    } else {
        down_fp32<<<2048, 256, 0, stream>>>(vf, kidx, kmask, W, bias, gamma,
                                            beta, mean, var, out, M);
    }
}